// Round 4
// baseline (66.584 us; speedup 1.0000x reference)
//
#include <hip/hip_runtime.h>
#include <stdint.h>

#define ROWS 8192     // B*N
#define D    128
#define CSPLIT 16
#define CPS  (ROWS / CSPLIT)    // 512 cols per split
#define BM   256
#define BN   32
#define NT   (CPS / BN)         // 16 col tiles per split
#define SQRT_LOG2E 1.2011224087864498f

typedef __bf16 bf16x8 __attribute__((ext_vector_type(8)));
typedef float  f32x4  __attribute__((ext_vector_type(4)));

typedef const __attribute__((address_space(1))) uint32_t guint;
typedef __attribute__((address_space(3))) uint32_t luint;

__device__ __forceinline__ void gload_lds16(const void* g, void* l) {
    __builtin_amdgcn_global_load_lds((guint*)g, (luint*)l, 16, 0, 0);
}

__device__ __forceinline__ ushort f2bf(float f) {
    union { float f; uint32_t u; } x; x.f = f;
    uint32_t r = x.u + 0x7FFFu + ((x.u >> 16) & 1u);
    return (ushort)(r >> 16);
}

// ---- Kernel 1: L2-normalize rows, cast to bf16; fk scaled by sqrt(log2e)
// so exp(logit) == exp2(sk) (saves one v_mul per Gram element). ----
__global__ __launch_bounds__(256) void k_norm(
    const float* __restrict__ fk, const float* __restrict__ fq,
    ushort* __restrict__ fkn, ushort* __restrict__ fqn)
{
    int gw = (blockIdx.x * 256 + threadIdx.x) >> 6;   // one wave per row
    int l  = threadIdx.x & 63;
    const float* src; ushort* dst; int r; float scale;
    if (gw < ROWS) { src = fk; dst = fkn; r = gw; scale = SQRT_LOG2E; }
    else           { src = fq; dst = fqn; r = gw - ROWS; scale = 1.0f; }
    float2 v = *reinterpret_cast<const float2*>(&src[r * D + l * 2]);
    float ss = v.x * v.x + v.y * v.y;
    #pragma unroll
    for (int m = 1; m < 64; m <<= 1) ss += __shfl_xor(ss, m, 64);
    float inv = scale / fmaxf(sqrtf(ss), 1e-12f);
    ushort2 o; o.x = f2bf(v.x * inv); o.y = f2bf(v.y * inv);
    *reinterpret_cast<ushort2*>(&dst[r * D + l * 2]) = o;
}

// ---- Kernel 2: fused Gram + exp + masked accumulation ----
// grid = (32, 16) = 512 blocks (2/CU), block = 512 (8 waves x 32 rows, rg=2).
// 4-buffer LDS ring, prefetch depth 3, counted vmcnt (never 0) + raw s_barrier.
__global__ __launch_bounds__(512, 4) void k_gram(
    const ushort* __restrict__ fkn, const ushort* __restrict__ fqn,
    float* __restrict__ pneg, float* __restrict__ ppos)
{
    __shared__ ushort lds[4][2][BN][128];   // 4 bufs x (fk 8KB + fq 8KB) = 64 KiB
    const int rt = blockIdx.x;
    const int cs = blockIdx.y;
    const int w  = threadIdx.x >> 6;        // 0..7
    const int l  = threadIdx.x & 63;
    const int lrow = l >> 4, lcol = l & 15;
    const int r0 = rt * BM;

    // Pre-swizzled global source offset (rule #21): gload_lds writes LDS
    // linearly; chunk L = tid -> row=L>>4, slot=L&15, src col = slot^(row&7).
    int soff;
    {
        int L = threadIdx.x;
        int row = L >> 4, slot = L & 15;
        soff = row * 256 + (slot ^ (row & 7)) * 16;
    }

    auto issue_stage = [&](int buf, int cbase) {
        gload_lds16((const char*)fkn + (size_t)cbase * 256 + soff, &lds[buf][0][0][0] + (size_t)threadIdx.x * 8);
        gload_lds16((const char*)fqn + (size_t)cbase * 256 + soff, &lds[buf][1][0][0] + (size_t)threadIdx.x * 8);
    };

    const int cbase0 = cs * CPS;
    issue_stage(0, cbase0);
    issue_stage(1, cbase0 + BN);
    issue_stage(2, cbase0 + 2 * BN);

    // A fragments (2 row-groups x 4 k-steps, both tensors), global->reg once.
    bf16x8 ak[2][4], aq[2][4];
    #pragma unroll
    for (int rg = 0; rg < 2; ++rg) {
        int arow = r0 + w * 32 + rg * 16 + lcol;      // A row: m = lane&15
        #pragma unroll
        for (int ks = 0; ks < 4; ++ks) {              // k = ks*32 + (lane>>4)*8 + e
            ak[rg][ks] = *reinterpret_cast<const bf16x8*>(fkn + arow * D + ks * 32 + lrow * 8);
            aq[rg][ks] = *reinterpret_cast<const bf16x8*>(fqn + arow * D + ks * 32 + lrow * 8);
        }
    }

    // wave's 32 rows lie in one aligned 64-row i-block => diag is wave-uniform
    const int diagc = (r0 + w * 32) & ~63;

    float accp[2][4] = {};
    float accn[2][4] = {};

    for (int t = 0; t < NT; ++t) {
        // counted wait: stages t+1,t+2 (4 loads) stay in flight; tile t landed.
        asm volatile("s_waitcnt vmcnt(4)" ::: "memory");
        __builtin_amdgcn_s_barrier();
        if (t + 3 < NT) issue_stage((t + 3) & 3, cbase0 + (t + 3) * BN);

        const int cbase = cbase0 + t * BN;
        const bool diag = ((cbase & ~63) == diagc);        // wave-uniform
        const ushort* bkb = &lds[t & 3][0][0][0];
        const ushort* bqb = &lds[t & 3][1][0][0];
        #pragma unroll
        for (int cc = 0; cc < 2; ++cc) {
            int brow = cc * 16 + lcol;                     // B row: n = lane&15
            bf16x8 bk[4], bq[4];
            #pragma unroll
            for (int ks = 0; ks < 4; ++ks) {
                int slot = (ks * 4 + lrow) ^ (brow & 7);
                bk[ks] = *reinterpret_cast<const bf16x8*>(bkb + brow * 128 + slot * 8);
                bq[ks] = *reinterpret_cast<const bf16x8*>(bqb + brow * 128 + slot * 8);
            }
            f32x4 sk0 = {0,0,0,0}, sk1 = {0,0,0,0}, sq0 = {0,0,0,0}, sq1 = {0,0,0,0};
            __builtin_amdgcn_s_setprio(1);
            #pragma unroll
            for (int ks = 0; ks < 4; ++ks) {
                sk0 = __builtin_amdgcn_mfma_f32_16x16x32_bf16(ak[0][ks], bk[ks], sk0, 0, 0, 0);
                sk1 = __builtin_amdgcn_mfma_f32_16x16x32_bf16(ak[1][ks], bk[ks], sk1, 0, 0, 0);
                sq0 = __builtin_amdgcn_mfma_f32_16x16x32_bf16(aq[0][ks], bq[ks], sq0, 0, 0, 0);
                sq1 = __builtin_amdgcn_mfma_f32_16x16x32_bf16(aq[1][ks], bq[ks], sq1, 0, 0, 0);
            }
            __builtin_amdgcn_s_setprio(0);
            // C layout: row = (lane>>4)*4 + e, col = lane&15
            if (diag) {
                #pragma unroll
                for (int e = 0; e < 4; ++e) {
                    accp[0][e] += __builtin_exp2f(sk0[e]);
                    accp[1][e] += __builtin_exp2f(sk1[e]);
                }
            } else {
                #pragma unroll
                for (int e = 0; e < 4; ++e) {
                    accn[0][e] += __builtin_exp2f(sk0[e]) * sq0[e];
                    accn[1][e] += __builtin_exp2f(sk1[e]) * sq1[e];
                }
            }
        }
    }

    // reduce across the 16 lanes sharing the same output rows
    #pragma unroll
    for (int m = 1; m <= 8; m <<= 1) {
        #pragma unroll
        for (int rg = 0; rg < 2; ++rg)
            #pragma unroll
            for (int e = 0; e < 4; ++e) {
                accp[rg][e] += __shfl_xor(accp[rg][e], m, 64);
                accn[rg][e] += __shfl_xor(accn[rg][e], m, 64);
            }
    }
    if (lcol == 0) {
        #pragma unroll
        for (int rg = 0; rg < 2; ++rg)
            #pragma unroll
            for (int e = 0; e < 4; ++e) {
                int gr = r0 + w * 32 + rg * 16 + lrow * 4 + e;
                ppos[cs * ROWS + gr] = accp[rg][e];
                pneg[cs * ROWS + gr] = accn[rg][e];
            }
    }
}

// ---- Kernel 3a: per-row loss, 32-block partial sums ----
__global__ __launch_bounds__(256) void k_loss1(
    const float* __restrict__ pneg, const float* __restrict__ ppos,
    float* __restrict__ bsum)
{
    int r = blockIdx.x * 256 + threadIdx.x;
    float pos = 0.f, neg = 0.f;
    #pragma unroll
    for (int p = 0; p < CSPLIT; ++p) { pos += ppos[p * ROWS + r]; neg += pneg[p * ROWS + r]; }
    float s = log1pf(neg / pos);
    #pragma unroll
    for (int m = 1; m < 64; m <<= 1) s += __shfl_xor(s, m, 64);
    __shared__ float red[4];
    if ((threadIdx.x & 63) == 0) red[threadIdx.x >> 6] = s;
    __syncthreads();
    if (threadIdx.x == 0) bsum[blockIdx.x] = red[0] + red[1] + red[2] + red[3];
}

// ---- Kernel 3b: final mean ----
__global__ void k_loss2(const float* __restrict__ bsum, float* __restrict__ out)
{
    int l = threadIdx.x;
    float s = (l < 32) ? bsum[l] : 0.f;
    #pragma unroll
    for (int m = 1; m < 64; m <<= 1) s += __shfl_xor(s, m, 64);
    if (l == 0) out[0] = s * (1.0f / ROWS);
}

extern "C" void kernel_launch(void* const* d_in, const int* in_sizes, int n_in,
                              void* d_out, int out_size, void* d_ws, size_t ws_size,
                              hipStream_t stream)
{
    const float* fk = (const float*)d_in[0];
    const float* fq = (const float*)d_in[1];
    ushort* fkn = (ushort*)d_ws;                        // 2 MB
    ushort* fqn = fkn + ROWS * D;                       // 2 MB
    float*  pneg = (float*)(fqn + ROWS * D);            // 512 KB
    float*  ppos = pneg + CSPLIT * ROWS;                // 512 KB
    float*  bsum = ppos + CSPLIT * ROWS;                // 128 B

    k_norm<<<(2 * ROWS) / 4, 256, 0, stream>>>(fk, fq, fkn, fqn);
    k_gram<<<dim3(ROWS / BM, CSPLIT), 512, 0, stream>>>(fkn, fqn, pneg, ppos);
    k_loss1<<<32, 256, 0, stream>>>(pneg, ppos, bsum);
    k_loss2<<<1, 64, 0, stream>>>(bsum, (float*)d_out);
}

// Round 5
// 56.950 us; speedup vs baseline: 1.1692x; 1.1692x over previous
//
#include <hip/hip_runtime.h>
#include <stdint.h>

#define ROWS 8192     // B*N
#define D    128
#define NSB  32       // 256-row super-blocks
#define BM   256
#define BN   64
#define NT   4        // 64-col tiles per super-block
#define NBLK (NSB * (NSB + 1) / 2)   // 528
#define SQRT_LOG2E 1.2011224087864498f

typedef __bf16 bf16x8 __attribute__((ext_vector_type(8)));
typedef float  f32x4  __attribute__((ext_vector_type(4)));

typedef const __attribute__((address_space(1))) uint32_t guint;
typedef __attribute__((address_space(3))) uint32_t luint;

__device__ __forceinline__ void gload_lds16(const void* g, void* l) {
    __builtin_amdgcn_global_load_lds((guint*)g, (luint*)l, 16, 0, 0);
}

__device__ __forceinline__ ushort f2bf(float f) {
    union { float f; uint32_t u; } x; x.f = f;
    uint32_t r = x.u + 0x7FFFu + ((x.u >> 16) & 1u);
    return (ushort)(r >> 16);
}

// ---- Kernel 1: L2-normalize rows, cast to bf16; fk scaled by sqrt(log2e)
// so exp(logit) == exp2(Gk) (saves one v_mul per Gram element). ----
__global__ __launch_bounds__(256) void k_norm(
    const float* __restrict__ fk, const float* __restrict__ fq,
    ushort* __restrict__ fkn, ushort* __restrict__ fqn)
{
    int gw = (blockIdx.x * 256 + threadIdx.x) >> 6;   // one wave per row
    int l  = threadIdx.x & 63;
    const float* src; ushort* dst; int r; float scale;
    if (gw < ROWS) { src = fk; dst = fkn; r = gw; scale = SQRT_LOG2E; }
    else           { src = fq; dst = fqn; r = gw - ROWS; scale = 1.0f; }
    float2 v = *reinterpret_cast<const float2*>(&src[r * D + l * 2]);
    float ss = v.x * v.x + v.y * v.y;
    #pragma unroll
    for (int m = 1; m < 64; m <<= 1) ss += __shfl_xor(ss, m, 64);
    float inv = scale / fmaxf(sqrtf(ss), 1e-12f);
    ushort2 o; o.x = f2bf(v.x * inv); o.y = f2bf(v.y * inv);
    *reinterpret_cast<ushort2*>(&dst[r * D + l * 2]) = o;
}

// ---- Kernel 2: symmetric fused Gram. One block per upper-tri 256x256
// super-tile (I,J). Off-diag tiles computed ONCE: row-sums -> block I rows
// (slot J), col-sums -> block J rows (slot I). Diag tiles computed in full
// (R2 structure) with the wave-uniform pos branch. ----
__global__ __launch_bounds__(512, 4) void k_gram(
    const ushort* __restrict__ fkn, const ushort* __restrict__ fqn,
    float* __restrict__ pneg, float* __restrict__ ppos)
{
    __shared__ ushort lds[2][2 * BN * D];   // 2 bufs x (fk 16KB + fq 16KB) = 64 KiB
    const int b = blockIdx.x;
    int I, J;
    if (b < NSB) { I = b; J = b; }
    else {
        int x = b - NSB, i = 0;
        while (x >= NSB - 1 - i) { x -= NSB - 1 - i; ++i; }
        I = i; J = i + 1 + x;
    }
    const bool isdiag = (I == J);
    const int w = threadIdx.x >> 6;         // 0..7
    const int l = threadIdx.x & 63;
    const int lrow = l >> 4, lcol = l & 15;
    const int r0 = I * BM;
    const int c0 = J * BM;

    // Pre-swizzled global source offsets (rule #21): gload_lds writes LDS
    // linearly; chunk L -> row=L>>4, slot=L&15, src col = slot^(row&7).
    int off[2];
    #pragma unroll
    for (int i = 0; i < 2; ++i) {
        int L = w * 128 + i * 64 + l;
        int row = L >> 4, slot = L & 15;
        off[i] = row * 256 + (slot ^ (row & 7)) * 16;
    }

    auto issue_stage = [&](int buf, int cbase) {
        const char* fkb = (const char*)fkn + (size_t)cbase * 256;
        const char* fqb = (const char*)fqn + (size_t)cbase * 256;
        ushort* lk = &lds[buf][w * 1024];
        ushort* lq = &lds[buf][BN * D + w * 1024];
        gload_lds16(fkb + off[0], lk);
        gload_lds16(fkb + off[1], lk + 512);
        gload_lds16(fqb + off[0], lq);
        gload_lds16(fqb + off[1], lq + 512);
    };

    issue_stage(0, c0);

    // A fragments (2 row-groups x 4 k-steps, both tensors), global->reg once.
    bf16x8 ak[2][4], aq[2][4];
    #pragma unroll
    for (int rg = 0; rg < 2; ++rg) {
        int arow = r0 + w * 32 + rg * 16 + lcol;      // A row: m = lane&15
        #pragma unroll
        for (int ks = 0; ks < 4; ++ks) {              // k = ks*32 + (lane>>4)*8 + e
            ak[rg][ks] = *reinterpret_cast<const bf16x8*>(fkn + arow * D + ks * 32 + lrow * 8);
            aq[rg][ks] = *reinterpret_cast<const bf16x8*>(fqn + arow * D + ks * 32 + lrow * 8);
        }
    }

    // wave's 32 rows lie in one aligned 64-row i-block => diag is wave-uniform
    const int diagc = (r0 + w * 32) & ~63;

    float accn[2][4] = {};
    // colacc: off-diag blocks = per-lane col partial sums, slot i = t*4+cc.
    // diag blocks = pos accumulator, slot rg*4+e (diag blocks never use cols).
    float colacc[16] = {};

    __syncthreads();

    #pragma unroll
    for (int t = 0; t < NT; ++t) {
        const int cur = t & 1;
        if (t + 1 < NT) issue_stage(cur ^ 1, c0 + (t + 1) * BN);  // async prefetch
        const int cbase = c0 + t * BN;
        const bool dtile = isdiag && (cbase == diagc);            // wave-uniform
        const ushort* bkb = &lds[cur][0];
        const ushort* bqb = &lds[cur][BN * D];
        #pragma unroll
        for (int cc = 0; cc < 4; ++cc) {
            int brow = cc * 16 + lcol;                            // B row: n = lane&15
            bf16x8 bk[4], bq[4];
            #pragma unroll
            for (int ks = 0; ks < 4; ++ks) {
                int slot = (ks * 4 + lrow) ^ (brow & 7);
                bk[ks] = *reinterpret_cast<const bf16x8*>(bkb + brow * 128 + slot * 8);
                bq[ks] = *reinterpret_cast<const bf16x8*>(bqb + brow * 128 + slot * 8);
            }
            f32x4 sk0 = {0,0,0,0}, sk1 = {0,0,0,0}, sq0 = {0,0,0,0}, sq1 = {0,0,0,0};
            __builtin_amdgcn_s_setprio(1);
            #pragma unroll
            for (int ks = 0; ks < 4; ++ks) {
                sk0 = __builtin_amdgcn_mfma_f32_16x16x32_bf16(ak[0][ks], bk[ks], sk0, 0, 0, 0);
                sk1 = __builtin_amdgcn_mfma_f32_16x16x32_bf16(ak[1][ks], bk[ks], sk1, 0, 0, 0);
                sq0 = __builtin_amdgcn_mfma_f32_16x16x32_bf16(aq[0][ks], bq[ks], sq0, 0, 0, 0);
                sq1 = __builtin_amdgcn_mfma_f32_16x16x32_bf16(aq[1][ks], bq[ks], sq1, 0, 0, 0);
            }
            __builtin_amdgcn_s_setprio(0);
            // C layout: row = (lane>>4)*4 + e, col = lane&15
            if (dtile) {
                #pragma unroll
                for (int e = 0; e < 4; ++e) {
                    colacc[0 * 4 + e] += __builtin_exp2f(sk0[e]);   // pos, rg=0
                    colacc[1 * 4 + e] += __builtin_exp2f(sk1[e]);   // pos, rg=1
                }
            } else {
                float psum = 0.f;
                #pragma unroll
                for (int e = 0; e < 4; ++e) {
                    float p0 = __builtin_exp2f(sk0[e]) * sq0[e];
                    float p1 = __builtin_exp2f(sk1[e]) * sq1[e];
                    accn[0][e] += p0;
                    accn[1][e] += p1;
                    psum += p0 + p1;
                }
                if (!isdiag) colacc[t * 4 + cc] += psum;            // block-uniform
            }
        }
        __syncthreads();   // next tile staged (vmcnt) + reads of cur done (lgkm)
    }

    // ---- row-sum reduce across the 16 lanes sharing the same output rows ----
    #pragma unroll
    for (int m = 1; m <= 8; m <<= 1) {
        #pragma unroll
        for (int rg = 0; rg < 2; ++rg)
            #pragma unroll
            for (int e = 0; e < 4; ++e)
                accn[rg][e] += __shfl_xor(accn[rg][e], m, 64);
    }
    if (isdiag) {
        #pragma unroll
        for (int m = 1; m <= 8; m <<= 1)
            #pragma unroll
            for (int i = 0; i < 8; ++i)
                colacc[i] += __shfl_xor(colacc[i], m, 64);
    }
    if (lcol == 0) {
        #pragma unroll
        for (int rg = 0; rg < 2; ++rg)
            #pragma unroll
            for (int e = 0; e < 4; ++e) {
                int gr = r0 + w * 32 + rg * 16 + lrow * 4 + e;
                pneg[J * ROWS + gr] = accn[rg][e];       // slot J for rows in I
                if (isdiag) ppos[gr] = colacc[rg * 4 + e];
            }
    }

    // ---- col-sum epilogue (off-diag only): rows of block J, slot I ----
    if (!isdiag) {
        #pragma unroll
        for (int i = 0; i < 16; ++i) {
            colacc[i] += __shfl_xor(colacc[i], 16, 64);
            colacc[i] += __shfl_xor(colacc[i], 32, 64);
        }
        float* colbuf = (float*)&lds[0][0];   // 8 KB; safe after final t-barrier
        if (l < 16) {
            #pragma unroll
            for (int i = 0; i < 16; ++i)                 // col = (i>>2)*64 + (i&3)*16 + l
                colbuf[w * 256 + (i >> 2) * 64 + (i & 3) * 16 + l] = colacc[i];
        }
        __syncthreads();
        if (threadIdx.x < 256) {
            int c = threadIdx.x;
            float s = 0.f;
            #pragma unroll
            for (int ww = 0; ww < 8; ++ww) s += colbuf[ww * 256 + c];
            pneg[I * ROWS + c0 + c] = s;                 // slot I for rows in J
        }
    }
}

// ---- Kernel 3a: per-row loss, 32-block partial sums ----
__global__ __launch_bounds__(256) void k_loss1(
    const float* __restrict__ pneg, const float* __restrict__ ppos,
    float* __restrict__ bsum)
{
    int r = blockIdx.x * 256 + threadIdx.x;
    float pos = ppos[r];
    float neg = 0.f;
    #pragma unroll
    for (int p = 0; p < NSB; ++p) neg += pneg[p * ROWS + r];
    float s = log1pf(neg / pos);
    #pragma unroll
    for (int m = 1; m < 64; m <<= 1) s += __shfl_xor(s, m, 64);
    __shared__ float red[4];
    if ((threadIdx.x & 63) == 0) red[threadIdx.x >> 6] = s;
    __syncthreads();
    if (threadIdx.x == 0) bsum[blockIdx.x] = red[0] + red[1] + red[2] + red[3];
}

// ---- Kernel 3b: final mean ----
__global__ void k_loss2(const float* __restrict__ bsum, float* __restrict__ out)
{
    int l = threadIdx.x;
    float s = (l < 32) ? bsum[l] : 0.f;
    #pragma unroll
    for (int m = 1; m < 64; m <<= 1) s += __shfl_xor(s, m, 64);
    if (l == 0) out[0] = s * (1.0f / ROWS);
}

extern "C" void kernel_launch(void* const* d_in, const int* in_sizes, int n_in,
                              void* d_out, int out_size, void* d_ws, size_t ws_size,
                              hipStream_t stream)
{
    const float* fk = (const float*)d_in[0];
    const float* fq = (const float*)d_in[1];
    ushort* fkn = (ushort*)d_ws;                        // 2 MB
    ushort* fqn = fkn + ROWS * D;                       // 2 MB
    float*  pneg = (float*)(fqn + ROWS * D);            // 32*8192*4 = 1 MB
    float*  ppos = pneg + NSB * ROWS;                   // 32 KB
    float*  bsum = ppos + ROWS;                         // 128 B

    k_norm<<<(2 * ROWS) / 4, 256, 0, stream>>>(fk, fq, fkn, fqn);
    k_gram<<<NBLK, 512, 0, stream>>>(fkn, fqn, pneg, ppos);
    k_loss1<<<32, 256, 0, stream>>>(pneg, ppos, bsum);
    k_loss2<<<1, 64, 0, stream>>>(bsum, (float*)d_out);
}